// Round 5
// baseline (163.255 us; speedup 1.0000x reference)
//
#include <hip/hip_runtime.h>
#include <hip/hip_bf16.h>

// Problem: B=2048, D=512, all fp32.
// q = query@Wq.T+bq ; k,v likewise. attn[b,i,j]=q_i*k_j (rank-1!),
// softmax over j, out[b,i] = sum_j softmax_j(q_i*k_j)*v_j.
//
// Round 5:
//  * presplit kernel: X,W fp32 -> bf16 hi/lo in d_ws (split ONCE, not 8x/elem)
//  * gemm: pure-bf16 MFMA, double-buffered LDS, ONE barrier per K-iter,
//    global loads issued 2 iterations ahead (C = Ahi*Bhi + Alo*Bhi + Ahi*Blo)
//  * attn: 4 i-rows per thread (128 thr/block) -> LDS bytes/elem halved,
//    fewer issue slots per exp. exp floor is 27.3 us device-wide.
//  * ws_size guard: fast path needs 28.3 MB; else fall back to round-4 gemm.

#define B_SZ 2048
#define D_SZ 512

typedef __attribute__((ext_vector_type(2))) float  f32x2;
typedef __attribute__((ext_vector_type(4))) float  f32x4;
typedef __attribute__((ext_vector_type(8))) short  bf16x8;   // MFMA A/B carrier
typedef __attribute__((ext_vector_type(4))) unsigned short u16x4;
typedef __attribute__((ext_vector_type(8))) unsigned short u16x8;

__device__ __forceinline__ float exp2_raw(float x) {
#if defined(__has_builtin) && __has_builtin(__builtin_amdgcn_exp2f)
    return __builtin_amdgcn_exp2f(x);
#else
    return exp2f(x);
#endif
}

// Truncation split: hi = top 16 bits of fp32; lo = bf16(trunc) of residual.
// |x - hi - lo| <= 2^-14 |x|
__device__ __forceinline__ void split1(float x, unsigned short& hi, unsigned short& lo) {
    unsigned int u = __float_as_uint(x);
    hi = (unsigned short)(u >> 16);
    float r = x - __uint_as_float(u & 0xFFFF0000u);
    lo = (unsigned short)(__float_as_uint(r) >> 16);
}

__device__ __forceinline__ void split4(const float4& x, u16x4& h, u16x4& l) {
    unsigned short hh, ll;
    split1(x.x, hh, ll); h.x = hh; l.x = ll;
    split1(x.y, hh, ll); h.y = hh; l.y = ll;
    split1(x.z, hh, ll); h.z = hh; l.z = ll;
    split1(x.w, hh, ll); h.w = hh; l.w = ll;
}

// ---------------------------------------------------------------------------
// Pre-split: all of X (3x 2048x512) and W (3x 512x512) fp32 -> bf16 hi/lo.
// One float4 per thread. Memory-bound: ~30 MB traffic, ~6 us.
// ---------------------------------------------------------------------------
#define XF4 (B_SZ * D_SZ / 4)   // 262144 float4 per X matrix
#define WF4 (D_SZ * D_SZ / 4)   // 65536 float4 per W matrix

__global__ __launch_bounds__(256) void presplit(
    const float* __restrict__ Xq, const float* __restrict__ Xk, const float* __restrict__ Xv,
    const float* __restrict__ Wq, const float* __restrict__ Wk, const float* __restrict__ Wv,
    unsigned short* __restrict__ Xhi, unsigned short* __restrict__ Xlo,
    unsigned short* __restrict__ Whi, unsigned short* __restrict__ Wlo)
{
    int idx = blockIdx.x * 256 + threadIdx.x;   // float4 index; grid covers 3*XF4+3*WF4
    const float* src;
    unsigned short *dhi, *dlo;
    int off;
    if (idx < 3 * XF4) {
        int which = idx / XF4;
        off = idx - which * XF4;
        src = (which == 0) ? Xq : (which == 1) ? Xk : Xv;
        dhi = Xhi + (size_t)which * B_SZ * D_SZ;
        dlo = Xlo + (size_t)which * B_SZ * D_SZ;
    } else {
        int j = idx - 3 * XF4;
        int which = j / WF4;
        off = j - which * WF4;
        src = (which == 0) ? Wq : (which == 1) ? Wk : Wv;
        dhi = Whi + (size_t)which * D_SZ * D_SZ;
        dlo = Wlo + (size_t)which * D_SZ * D_SZ;
    }
    float4 x = ((const float4*)src)[off];
    u16x4 h, l;
    split4(x, h, l);
    ((u16x4*)dhi)[off] = h;
    ((u16x4*)dlo)[off] = l;
}

// ---------------------------------------------------------------------------
// Fast-path GEMM: Y = X @ W^T + bias from pre-split bf16 hi/lo.
// 64x64 tile, 256 thr (4 waves 2x2), BK=32, double-buffered LDS,
// one barrier per iter, staging loads issued 2 iterations ahead.
// ---------------------------------------------------------------------------
__global__ __launch_bounds__(256) void qkv_gemm_bf16(
    const unsigned short* __restrict__ Xhi, const unsigned short* __restrict__ Xlo,
    const unsigned short* __restrict__ Whi, const unsigned short* __restrict__ Wlo,
    const float* __restrict__ bq, const float* __restrict__ bk, const float* __restrict__ bv,
    float* __restrict__ qkv_out)
{
    const int which = blockIdx.z;
    const unsigned short* __restrict__ Ah = Xhi + (size_t)which * B_SZ * D_SZ;
    const unsigned short* __restrict__ Al = Xlo + (size_t)which * B_SZ * D_SZ;
    const unsigned short* __restrict__ Bh = Whi + (size_t)which * D_SZ * D_SZ;
    const unsigned short* __restrict__ Bl = Wlo + (size_t)which * D_SZ * D_SZ;
    const float* __restrict__ bias = (which == 0) ? bq : (which == 1) ? bk : bv;
    float* __restrict__ Y = qkv_out + (size_t)which * B_SZ * D_SZ;

    const int t    = threadIdx.x;
    const int lane = t & 63;
    const int wv   = t >> 6;
    const int l15  = lane & 15;
    const int quad = lane >> 4;
    const int wm   = (wv >> 1) * 32;
    const int wn   = (wv & 1) * 32;
    const int m0   = blockIdx.x * 64;
    const int n0   = blockIdx.y * 64;

    // 2 buffers x 4 tiles x [64][40] shorts = 40 KB (pad 40: b128 2-way max)
    __shared__ unsigned short AsH[2][64][40], AsL[2][64][40];
    __shared__ unsigned short BsH[2][64][40], BsL[2][64][40];

    f32x4 acc[2][2] = {{{0.f,0.f,0.f,0.f},{0.f,0.f,0.f,0.f}},
                       {{0.f,0.f,0.f,0.f},{0.f,0.f,0.f,0.f}}};

    // staging: thread t handles row sr, 16B chunk sc (64 rows x 4 chunks)
    const int sr = t >> 2;
    const int sc = (t & 3) * 8;                 // shorts
    const unsigned short* pAh = Ah + (size_t)(m0 + sr) * D_SZ + sc;
    const unsigned short* pAl = Al + (size_t)(m0 + sr) * D_SZ + sc;
    const unsigned short* pBh = Bh + (size_t)(n0 + sr) * D_SZ + sc;
    const unsigned short* pBl = Bl + (size_t)(n0 + sr) * D_SZ + sc;

    u16x8 rAh, rAl, rBh, rBl;

#define LOADC(kpos)  do { \
        rAh = *(const u16x8*)(pAh + (kpos)); \
        rAl = *(const u16x8*)(pAl + (kpos)); \
        rBh = *(const u16x8*)(pBh + (kpos)); \
        rBl = *(const u16x8*)(pBl + (kpos)); } while (0)
#define STOREC(bf)   do { \
        *(u16x8*)&AsH[bf][sr][sc] = rAh; \
        *(u16x8*)&AsL[bf][sr][sc] = rAl; \
        *(u16x8*)&BsH[bf][sr][sc] = rBh; \
        *(u16x8*)&BsL[bf][sr][sc] = rBl; } while (0)

    LOADC(0);
    STOREC(0);
    LOADC(32);
    __syncthreads();

    for (int kc = 0; kc < 16; ++kc) {
        const int cur = kc & 1;

        bf16x8 ah0 = *(const bf16x8*)&AsH[cur][wm + l15     ][quad * 8];
        bf16x8 ah1 = *(const bf16x8*)&AsH[cur][wm + 16 + l15][quad * 8];
        bf16x8 al0 = *(const bf16x8*)&AsL[cur][wm + l15     ][quad * 8];
        bf16x8 al1 = *(const bf16x8*)&AsL[cur][wm + 16 + l15][quad * 8];
        bf16x8 bh0 = *(const bf16x8*)&BsH[cur][wn + l15     ][quad * 8];
        bf16x8 bh1 = *(const bf16x8*)&BsH[cur][wn + 16 + l15][quad * 8];
        bf16x8 bl0 = *(const bf16x8*)&BsL[cur][wn + l15     ][quad * 8];
        bf16x8 bl1 = *(const bf16x8*)&BsL[cur][wn + 16 + l15][quad * 8];

        if (kc + 1 < 16) STOREC(1 - cur);        // chunk kc+1 (loads 1 iter old)
        if (kc + 2 < 16) LOADC((kc + 2) * 32);   // issue 2 iterations ahead

        acc[0][0] = __builtin_amdgcn_mfma_f32_16x16x32_bf16(ah0, bh0, acc[0][0], 0, 0, 0);
        acc[0][1] = __builtin_amdgcn_mfma_f32_16x16x32_bf16(ah0, bh1, acc[0][1], 0, 0, 0);
        acc[1][0] = __builtin_amdgcn_mfma_f32_16x16x32_bf16(ah1, bh0, acc[1][0], 0, 0, 0);
        acc[1][1] = __builtin_amdgcn_mfma_f32_16x16x32_bf16(ah1, bh1, acc[1][1], 0, 0, 0);
        acc[0][0] = __builtin_amdgcn_mfma_f32_16x16x32_bf16(al0, bh0, acc[0][0], 0, 0, 0);
        acc[0][1] = __builtin_amdgcn_mfma_f32_16x16x32_bf16(al0, bh1, acc[0][1], 0, 0, 0);
        acc[1][0] = __builtin_amdgcn_mfma_f32_16x16x32_bf16(al1, bh0, acc[1][0], 0, 0, 0);
        acc[1][1] = __builtin_amdgcn_mfma_f32_16x16x32_bf16(al1, bh1, acc[1][1], 0, 0, 0);
        acc[0][0] = __builtin_amdgcn_mfma_f32_16x16x32_bf16(ah0, bl0, acc[0][0], 0, 0, 0);
        acc[0][1] = __builtin_amdgcn_mfma_f32_16x16x32_bf16(ah0, bl1, acc[0][1], 0, 0, 0);
        acc[1][0] = __builtin_amdgcn_mfma_f32_16x16x32_bf16(ah1, bl0, acc[1][0], 0, 0, 0);
        acc[1][1] = __builtin_amdgcn_mfma_f32_16x16x32_bf16(ah1, bl1, acc[1][1], 0, 0, 0);

        __syncthreads();
    }
#undef LOADC
#undef STOREC

    // epilogue: C/D layout col=lane&15, row=quad*4+reg (m89/m91-verified)
#pragma unroll
    for (int ni = 0; ni < 2; ++ni) {
        const int col = n0 + wn + ni * 16 + l15;
        const float bb = bias[col];
#pragma unroll
        for (int mi = 0; mi < 2; ++mi) {
            const int row = m0 + wm + mi * 16 + quad * 4;
#pragma unroll
            for (int r = 0; r < 4; ++r) {
                Y[(size_t)(row + r) * D_SZ + col] = acc[mi][ni][r] + bb;
            }
        }
    }
}

// ---------------------------------------------------------------------------
// Fallback GEMM (round-4): in-kernel split, used only if ws_size too small.
// ---------------------------------------------------------------------------
__global__ __launch_bounds__(256) void qkv_gemm_mfma(
    const float* __restrict__ Xq, const float* __restrict__ Xk, const float* __restrict__ Xv,
    const float* __restrict__ Wq, const float* __restrict__ bq,
    const float* __restrict__ Wk, const float* __restrict__ bk,
    const float* __restrict__ Wv, const float* __restrict__ bv,
    float* __restrict__ qkv_out)
{
    const int which = blockIdx.z;
    const float* __restrict__ X    = (which == 0) ? Xq : (which == 1) ? Xk : Xv;
    const float* __restrict__ W    = (which == 0) ? Wq : (which == 1) ? Wk : Wv;
    const float* __restrict__ bias = (which == 0) ? bq : (which == 1) ? bk : bv;
    float* __restrict__ Y = qkv_out + (size_t)which * B_SZ * D_SZ;

    const int t    = threadIdx.x;
    const int lane = t & 63;
    const int wv   = t >> 6;
    const int l15  = lane & 15;
    const int quad = lane >> 4;
    const int wm   = (wv >> 1) * 32;
    const int wn   = (wv & 1) * 32;
    const int m0   = blockIdx.x * 64;
    const int n0   = blockIdx.y * 64;

    __shared__ unsigned short Ahi[64][40], Alo[64][40];
    __shared__ unsigned short Bhi[64][40], Blo[64][40];

    f32x4 acc[2][2] = {{{0.f,0.f,0.f,0.f},{0.f,0.f,0.f,0.f}},
                       {{0.f,0.f,0.f,0.f},{0.f,0.f,0.f,0.f}}};

    const int r0 = t >> 3;
    const int c0 = (t & 7) * 4;
    const int r1 = r0 + 32;

    const float* Xp0 = &X[(size_t)(m0 + r0) * D_SZ + c0];
    const float* Xp1 = &X[(size_t)(m0 + r1) * D_SZ + c0];
    const float* Wp0 = &W[(size_t)(n0 + r0) * D_SZ + c0];
    const float* Wp1 = &W[(size_t)(n0 + r1) * D_SZ + c0];

    float4 xa0 = *(const float4*)(Xp0);
    float4 xa1 = *(const float4*)(Xp1);
    float4 wa0 = *(const float4*)(Wp0);
    float4 wa1 = *(const float4*)(Wp1);

    for (int kk = 0; kk < D_SZ; kk += 32) {
        __syncthreads();
        u16x4 h, l;
        split4(xa0, h, l); *(u16x4*)&Ahi[r0][c0] = h; *(u16x4*)&Alo[r0][c0] = l;
        split4(xa1, h, l); *(u16x4*)&Ahi[r1][c0] = h; *(u16x4*)&Alo[r1][c0] = l;
        split4(wa0, h, l); *(u16x4*)&Bhi[r0][c0] = h; *(u16x4*)&Blo[r0][c0] = l;
        split4(wa1, h, l); *(u16x4*)&Bhi[r1][c0] = h; *(u16x4*)&Blo[r1][c0] = l;
        __syncthreads();

        if (kk + 32 < D_SZ) {
            xa0 = *(const float4*)(Xp0 + kk + 32);
            xa1 = *(const float4*)(Xp1 + kk + 32);
            wa0 = *(const float4*)(Wp0 + kk + 32);
            wa1 = *(const float4*)(Wp1 + kk + 32);
        }

        bf16x8 ah0 = *(const bf16x8*)&Ahi[wm + l15     ][quad * 8];
        bf16x8 ah1 = *(const bf16x8*)&Ahi[wm + 16 + l15][quad * 8];
        bf16x8 al0 = *(const bf16x8*)&Alo[wm + l15     ][quad * 8];
        bf16x8 al1 = *(const bf16x8*)&Alo[wm + 16 + l15][quad * 8];
        bf16x8 bh0 = *(const bf16x8*)&Bhi[wn + l15     ][quad * 8];
        bf16x8 bh1 = *(const bf16x8*)&Bhi[wn + 16 + l15][quad * 8];
        bf16x8 bl0 = *(const bf16x8*)&Blo[wn + l15     ][quad * 8];
        bf16x8 bl1 = *(const bf16x8*)&Blo[wn + 16 + l15][quad * 8];

        acc[0][0] = __builtin_amdgcn_mfma_f32_16x16x32_bf16(ah0, bh0, acc[0][0], 0, 0, 0);
        acc[0][0] = __builtin_amdgcn_mfma_f32_16x16x32_bf16(al0, bh0, acc[0][0], 0, 0, 0);
        acc[0][0] = __builtin_amdgcn_mfma_f32_16x16x32_bf16(ah0, bl0, acc[0][0], 0, 0, 0);
        acc[0][1] = __builtin_amdgcn_mfma_f32_16x16x32_bf16(ah0, bh1, acc[0][1], 0, 0, 0);
        acc[0][1] = __builtin_amdgcn_mfma_f32_16x16x32_bf16(al0, bh1, acc[0][1], 0, 0, 0);
        acc[0][1] = __builtin_amdgcn_mfma_f32_16x16x32_bf16(ah0, bl1, acc[0][1], 0, 0, 0);
        acc[1][0] = __builtin_amdgcn_mfma_f32_16x16x32_bf16(ah1, bh0, acc[1][0], 0, 0, 0);
        acc[1][0] = __builtin_amdgcn_mfma_f32_16x16x32_bf16(al1, bh0, acc[1][0], 0, 0, 0);
        acc[1][0] = __builtin_amdgcn_mfma_f32_16x16x32_bf16(ah1, bl0, acc[1][0], 0, 0, 0);
        acc[1][1] = __builtin_amdgcn_mfma_f32_16x16x32_bf16(ah1, bh1, acc[1][1], 0, 0, 0);
        acc[1][1] = __builtin_amdgcn_mfma_f32_16x16x32_bf16(al1, bh1, acc[1][1], 0, 0, 0);
        acc[1][1] = __builtin_amdgcn_mfma_f32_16x16x32_bf16(ah1, bl1, acc[1][1], 0, 0, 0);
    }

#pragma unroll
    for (int ni = 0; ni < 2; ++ni) {
        const int col = n0 + wn + ni * 16 + l15;
        const float bb = bias[col];
#pragma unroll
        for (int mi = 0; mi < 2; ++mi) {
            const int row = m0 + wm + mi * 16 + quad * 4;
#pragma unroll
            for (int r = 0; r < 4; ++r) {
                Y[(size_t)(row + r) * D_SZ + col] = acc[mi][ni][r] + bb;
            }
        }
    }
}

// ---------------------------------------------------------------------------
// attn: out[b,i] = sum_j exp(q_i*k_j - m_i)*v_j / den; m_i via kmax/kmin.
// 128 threads (2 waves) per b; 4 i-rows per thread so each ds_read_b128
// (2 j's) serves 8 elements. log2 domain. Packed f32x2 acc per row over the
// two j's of a chunk.
// ---------------------------------------------------------------------------
__global__ __launch_bounds__(128) void attn_kernel4(
    const float* __restrict__ qkv, float* __restrict__ out)
{
    const int b = blockIdx.x;
    const int t = threadIdx.x;

    const float* __restrict__ q = qkv + (size_t)b * D_SZ;
    const float* __restrict__ k = qkv + (size_t)B_SZ * D_SZ + (size_t)b * D_SZ;
    const float* __restrict__ v = qkv + (size_t)2 * B_SZ * D_SZ + (size_t)b * D_SZ;

    __shared__ float kv[D_SZ * 2];          // interleaved k*L, v
    __shared__ float redmax[2], redmin[2];

    const float L = 1.44269504088896340736f;  // log2(e)

    // 4 q rows per thread (issue early)
    float qr[4], cr[4];
#pragma unroll
    for (int r = 0; r < 4; ++r) qr[r] = q[t + r * 128];

    // stage k,v: one float4 of each per thread
    float4 k4 = *(const float4*)&k[4 * t];
    float4 v4 = *(const float4*)&v[4 * t];
    k4.x *= L; k4.y *= L; k4.z *= L; k4.w *= L;
    float4 s0 = make_float4(k4.x, v4.x, k4.y, v4.y);
    float4 s1 = make_float4(k4.z, v4.z, k4.w, v4.w);
    *(float4*)&kv[8 * t]     = s0;
    *(float4*)&kv[8 * t + 4] = s1;

    float kmaxL = fmaxf(fmaxf(k4.x, k4.y), fmaxf(k4.z, k4.w));
    float kminL = fminf(fminf(k4.x, k4.y), fminf(k4.z, k4.w));
#pragma unroll
    for (int off = 32; off > 0; off >>= 1) {
        kmaxL = fmaxf(kmaxL, __shfl_xor(kmaxL, off));
        kminL = fminf(kminL, __shfl_xor(kminL, off));
    }
    const int wave = t >> 6;
    if ((t & 63) == 0) { redmax[wave] = kmaxL; redmin[wave] = kminL; }
    __syncthreads();   // also publishes kv[]
    kmaxL = fmaxf(redmax[0], redmax[1]);
    kminL = fminf(redmin[0], redmin[1]);

#pragma unroll
    for (int r = 0; r < 4; ++r)
        cr[r] = (qr[r] >= 0.f) ? -(qr[r] * kmaxL) : -(qr[r] * kminL);

    f32x2 den[4] = {{0.f,0.f},{0.f,0.f},{0.f,0.f},{0.f,0.f}};
    f32x2 num[4] = {{0.f,0.f},{0.f,0.f},{0.f,0.f},{0.f,0.f}};

#pragma unroll 4
    for (int j = 0; j < D_SZ; j += 2) {
        f32x4 p = *(const f32x4*)&kv[2 * j];   // kL_j, v_j, kL_{j+1}, v_{j+1}
        f32x2 vv = {p.y, p.w};
#pragma unroll
        for (int r = 0; r < 4; ++r) {
            f32x2 e = {exp2_raw(fmaf(qr[r], p.x, cr[r])),
                       exp2_raw(fmaf(qr[r], p.z, cr[r]))};
            den[r] += e;
            num[r] += e * vv;
        }
    }
#pragma unroll
    for (int r = 0; r < 4; ++r)
        out[(size_t)b * D_SZ + t + r * 128] = (num[r].x + num[r].y) / (den[r].x + den[r].y);
}

extern "C" void kernel_launch(void* const* d_in, const int* in_sizes, int n_in,
                              void* d_out, int out_size, void* d_ws, size_t ws_size,
                              hipStream_t stream) {
    const float* query = (const float*)d_in[0];
    const float* key_  = (const float*)d_in[1];
    const float* value = (const float*)d_in[2];
    const float* Wq    = (const float*)d_in[3];
    const float* bq    = (const float*)d_in[4];
    const float* Wk    = (const float*)d_in[5];
    const float* bk    = (const float*)d_in[6];
    const float* Wv    = (const float*)d_in[7];
    const float* bv    = (const float*)d_in[8];
    float* out = (float*)d_out;

    // ws layout: qkv fp32 [3][B][D] | Xhi | Xlo (bf16 [3][B][D]) | Whi | Wlo
    const size_t qkv_bytes = (size_t)3 * B_SZ * D_SZ * 4;          // 12.58 MB
    const size_t xs_bytes  = (size_t)3 * B_SZ * D_SZ * 2;          // 6.29 MB
    const size_t ws_bytes_w= (size_t)3 * D_SZ * D_SZ * 2;          // 1.57 MB
    const size_t need = qkv_bytes + 2 * xs_bytes + 2 * ws_bytes_w; // 28.3 MB

    float* qkv = (float*)d_ws;

    if (ws_size >= need) {
        unsigned short* Xhi = (unsigned short*)((char*)d_ws + qkv_bytes);
        unsigned short* Xlo = (unsigned short*)((char*)d_ws + qkv_bytes + xs_bytes);
        unsigned short* Whi = (unsigned short*)((char*)d_ws + qkv_bytes + 2 * xs_bytes);
        unsigned short* Wlo = (unsigned short*)((char*)d_ws + qkv_bytes + 2 * xs_bytes + ws_bytes_w);

        const int nF4 = 3 * XF4 + 3 * WF4;       // 983040
        presplit<<<nF4 / 256, 256, 0, stream>>>(query, key_, value, Wq, Wk, Wv,
                                                Xhi, Xlo, Whi, Wlo);
        dim3 g1(B_SZ / 64, D_SZ / 64, 3);
        qkv_gemm_bf16<<<g1, 256, 0, stream>>>(Xhi, Xlo, Whi, Wlo, bq, bk, bv, qkv);
    } else {
        dim3 g1(B_SZ / 64, D_SZ / 64, 3);
        qkv_gemm_mfma<<<g1, 256, 0, stream>>>(query, key_, value, Wq, bq, Wk, bk, Wv, bv, qkv);
    }
    attn_kernel4<<<B_SZ, 128, 0, stream>>>(qkv, out);
}